// Round 1
// baseline (5487.137 us; speedup 1.0000x reference)
//
#include <hip/hip_runtime.h>
#include <math.h>

#define Bz 32
#define Tz 512
#define Ez 256
#define Hz 512
#define FCH 446   // 180 conv + 10 rev + 256 x

__device__ __forceinline__ float sigf(float x){ return 1.0f/(1.0f + __expf(-x)); }
__device__ __forceinline__ float tanhfast(float x){ return 1.0f - 2.0f/(__expf(2.0f*x) + 1.0f); }

// ---------------- WhT transpose: WhT[c*512 + k] = Wh[k*2048 + c] ----------------
__global__ __launch_bounds__(256) void k_transpose_wh(const float* __restrict__ Wh, float* __restrict__ WhT){
  int idx = blockIdx.x*256 + threadIdx.x;      // 512*2048 = 1,048,576
  int k = idx >> 11, c = idx & 2047;
  WhT[c*512 + k] = Wh[idx];
}

// ---------------- conv (3 kernels, SAME pad) + rxw = x_rev @ rev_Wx ----------------
// block: one (b, 32-t tile). feat[t-1][b][c] = conved[b][t][c]; rxw[(511-t)][b][j]
__global__ __launch_bounds__(256) void k_conv(
    const float* __restrict__ x,
    const float* __restrict__ w1, const float* __restrict__ b1,
    const float* __restrict__ w2, const float* __restrict__ b2,
    const float* __restrict__ w3, const float* __restrict__ b3,
    const float* __restrict__ rwx,
    float* __restrict__ feat, float* __restrict__ rxw)
{
  __shared__ __align__(16) float xs[256*40];   // xs[e*40 + i] = x[b][t0-2+i], i in 0..35
  int b  = blockIdx.x >> 4;
  int t0 = (blockIdx.x & 15) * 32;
  int tid = threadIdx.x;
  for (int i = 0; i < 36; ++i){
    int t = t0 - 2 + i;
    xs[tid*40 + i] = (t >= 0 && t < Tz) ? x[(b*Tz + t)*Ez + tid] : 0.0f;
  }
  __syncthreads();
  int tq = tid & 7, cs = tid >> 3;             // 8 t-quads x 32 c-slots
  float acc[6][4];
  float racc[2][4];
  #pragma unroll
  for (int ci = 0; ci < 6; ++ci){
    int c = cs + 32*ci;
    float bv = 0.0f;
    if (c < 60) bv = b1[c];
    else if (c < 120) bv = b2[c-60];
    else if (c < 180) bv = b3[c-120];
    acc[ci][0]=acc[ci][1]=acc[ci][2]=acc[ci][3]=bv;
  }
  #pragma unroll
  for (int ji = 0; ji < 2; ++ji){ racc[ji][0]=racc[ji][1]=racc[ji][2]=racc[ji][3]=0.0f; }

  for (int e = 0; e < 256; ++e){
    const float* xr = &xs[e*40 + 4*tq];
    float4 wa = *(const float4*)(xr);
    float4 wb = *(const float4*)(xr + 4);
    float wd[8] = {wa.x, wa.y, wa.z, wa.w, wb.x, wb.y, wb.z, wb.w};
    #pragma unroll
    for (int ci = 0; ci < 6; ++ci){
      int c = cs + 32*ci;
      if (c < 60){
        #pragma unroll
        for (int k = 0; k < 3; ++k){
          float wv = w1[(k*256 + e)*60 + c];
          #pragma unroll
          for (int j = 0; j < 4; ++j) acc[ci][j] = fmaf(wd[1 + j + k], wv, acc[ci][j]);
        }
      } else if (c < 120){
        int cc = c - 60;
        #pragma unroll
        for (int k = 0; k < 4; ++k){
          float wv = w2[(k*256 + e)*60 + cc];
          #pragma unroll
          for (int j = 0; j < 4; ++j) acc[ci][j] = fmaf(wd[1 + j + k], wv, acc[ci][j]);
        }
      } else if (c < 180){
        int cc = c - 120;
        #pragma unroll
        for (int k = 0; k < 5; ++k){
          float wv = w3[(k*256 + e)*60 + cc];
          #pragma unroll
          for (int j = 0; j < 4; ++j) acc[ci][j] = fmaf(wd[j + k], wv, acc[ci][j]);
        }
      }
    }
    #pragma unroll
    for (int ji = 0; ji < 2; ++ji){
      int jc = cs + 32*ji;
      if (jc < 40){
        float wv = rwx[e*40 + jc];
        #pragma unroll
        for (int j = 0; j < 4; ++j) racc[ji][j] = fmaf(wd[2 + j], wv, racc[ji][j]);
      }
    }
  }
  #pragma unroll
  for (int ci = 0; ci < 6; ++ci){
    int c = cs + 32*ci;
    if (c < 180){
      #pragma unroll
      for (int j = 0; j < 4; ++j){
        int t = t0 + 4*tq + j;
        if (t >= 1) feat[((t-1)*Bz + b)*FCH + c] = acc[ci][j];
      }
    }
  }
  #pragma unroll
  for (int ji = 0; ji < 2; ++ji){
    int jc = cs + 32*ji;
    if (jc < 40){
      #pragma unroll
      for (int j = 0; j < 4; ++j){
        int t = t0 + 4*tq + j;
        rxw[((511 - t)*Bz + b)*40 + jc] = racc[ji][j];
      }
    }
  }
}

// ---------------- copy x into feat[...,190:446] ----------------
__global__ __launch_bounds__(256) void k_featx(const float* __restrict__ x, float* __restrict__ feat){
  int bt = blockIdx.x;
  int b = bt >> 9, t = bt & 511;
  feat[(t*Bz + b)*FCH + 190 + threadIdx.x] = x[(b*Tz + t)*Ez + threadIdx.x];
}

// ---------------- reverse LSTM (hidden 10), one wave per batch row ----------------
__global__ __launch_bounds__(64) void k_rev(const float* __restrict__ rxw,
    const float* __restrict__ revWh, const float* __restrict__ revb, float* __restrict__ feat){
  int b = blockIdx.x;
  int j = threadIdx.x;
  float wreg[10];
  float bias = 0.0f;
  #pragma unroll
  for (int k = 0; k < 10; ++k) wreg[k] = 0.0f;
  if (j < 40){
    bias = revb[j];
    #pragma unroll
    for (int k = 0; k < 10; ++k) wreg[k] = revWh[k*40 + j];
  }
  float h[10];
  #pragma unroll
  for (int k = 0; k < 10; ++k) h[k] = 0.0f;
  float c = 0.0f;
  for (int s = 0; s < Tz; ++s){
    float z = bias + ((j < 40) ? rxw[(s*Bz + b)*40 + j] : 0.0f);
    #pragma unroll
    for (int k = 0; k < 10; ++k) z = fmaf(h[k], wreg[k], z);
    float a = (j >= 20 && j < 30) ? tanhfast(z) : sigf(z);
    float af = __shfl(a, j + 10);
    float ag = __shfl(a, j + 20);
    float ao = __shfl(a, j + 30);
    if (j < 10) c = af*c + a*ag;
    float hn = ao * tanhfast(c);
    #pragma unroll
    for (int k = 0; k < 10; ++k) h[k] = __shfl(hn, k);
    if (j < 10 && s >= 1) feat[((s-1)*Bz + b)*FCH + 180 + j] = hn;
  }
}

// ---------------- hid = relu(feat @ d0_W + d0_b): 32 rows x 100 cols per block ----------------
__global__ __launch_bounds__(256) void k_hid(const float* __restrict__ feat,
    const float* __restrict__ d0W, const float* __restrict__ d0b, float* __restrict__ hid){
  __shared__ __align__(16) float fT[446*36];   // fT[ch*36 + r]
  int r0 = blockIdx.x * 32;
  int tid = threadIdx.x;
  for (int r = 0; r < 32; ++r){
    fT[tid*36 + r] = feat[(r0 + r)*FCH + tid];
    if (tid < 190) fT[(tid + 256)*36 + r] = feat[(r0 + r)*FCH + tid + 256];
  }
  __syncthreads();
  int cs = tid & 31, rq = tid >> 5;            // 32 c-slots (4 cols each), 8 row-quads
  if (cs < 25){
    float4 accv[4];
    #pragma unroll
    for (int jc = 0; jc < 4; ++jc) accv[jc] = make_float4(0.f,0.f,0.f,0.f);
    for (int k = 0; k < 446; ++k){
      float4 xv = *(const float4*)&fT[k*36 + 4*rq];
      float4 wv = *(const float4*)&d0W[k*100 + 4*cs];
      accv[0].x = fmaf(xv.x, wv.x, accv[0].x); accv[0].y = fmaf(xv.y, wv.x, accv[0].y);
      accv[0].z = fmaf(xv.z, wv.x, accv[0].z); accv[0].w = fmaf(xv.w, wv.x, accv[0].w);
      accv[1].x = fmaf(xv.x, wv.y, accv[1].x); accv[1].y = fmaf(xv.y, wv.y, accv[1].y);
      accv[1].z = fmaf(xv.z, wv.y, accv[1].z); accv[1].w = fmaf(xv.w, wv.y, accv[1].w);
      accv[2].x = fmaf(xv.x, wv.z, accv[2].x); accv[2].y = fmaf(xv.y, wv.z, accv[2].y);
      accv[2].z = fmaf(xv.z, wv.z, accv[2].z); accv[2].w = fmaf(xv.w, wv.z, accv[2].w);
      accv[3].x = fmaf(xv.x, wv.w, accv[3].x); accv[3].y = fmaf(xv.y, wv.w, accv[3].y);
      accv[3].z = fmaf(xv.z, wv.w, accv[3].z); accv[3].w = fmaf(xv.w, wv.w, accv[3].w);
    }
    #pragma unroll
    for (int i = 0; i < 4; ++i){
      int row = r0 + 4*rq + i;
      float4 o;
      float vi[4] = { i==0?accv[0].x:(i==1?accv[0].y:(i==2?accv[0].z:accv[0].w)),
                      i==0?accv[1].x:(i==1?accv[1].y:(i==2?accv[1].z:accv[1].w)),
                      i==0?accv[2].x:(i==1?accv[2].y:(i==2?accv[2].z:accv[2].w)),
                      i==0?accv[3].x:(i==1?accv[3].y:(i==2?accv[3].z:accv[3].w)) };
      o.x = fmaxf(vi[0] + d0b[4*cs+0], 0.0f);
      o.y = fmaxf(vi[1] + d0b[4*cs+1], 0.0f);
      o.z = fmaxf(vi[2] + d0b[4*cs+2], 0.0f);
      o.w = fmaxf(vi[3] + d0b[4*cs+3], 0.0f);
      *(float4*)&hid[row*100 + 4*cs] = o;
    }
  }
}

// ---------------- pi + gumbel softmax -> d0,d1 (64 rows per block) ----------------
__global__ __launch_bounds__(128) void k_pi(const float* __restrict__ hid,
    const float* __restrict__ d1W, const float* __restrict__ d1b,
    const float* __restrict__ gum, float* __restrict__ d0a, float* __restrict__ d1a){
  __shared__ float hidL[64*100];
  int r0 = blockIdx.x * 64;
  int tid = threadIdx.x;
  for (int i = 0; i < 50; ++i) hidL[tid + 128*i] = hid[r0*100 + tid + 128*i];
  __syncthreads();
  int r = tid >> 1, pp = tid & 1;
  float s = d1b[pp];
  for (int m = 0; m < 100; ++m) s = fmaf(hidL[r*100 + m], d1W[m*2 + pp], s);
  int row = r0 + r;
  float a = (s + gum[row*2 + pp]) / 1e-5f;
  float other = __shfl_xor(a, 1);
  float mx = fmaxf(a, other);
  float ea = expf(a - mx), eb = expf(other - mx);
  float d = ea / (ea + eb);
  if (pp == 0) d0a[row] = d; else d1a[row] = d;
}

// ---------------- xzT[t][col][b] = x[b][t] @ cell_Wx + cell_b ----------------
// block: one t (32 b rows) x 128 cols
__global__ __launch_bounds__(256) void k_xz(const float* __restrict__ x,
    const float* __restrict__ Wx, const float* __restrict__ cb, float* __restrict__ xzT){
  __shared__ __align__(16) float xT[256*36];   // xT[e*36 + b]
  int t  = blockIdx.x >> 4;
  int c0 = (blockIdx.x & 15) * 128;
  int tid = threadIdx.x;
  for (int b = 0; b < 32; ++b){
    xT[tid*36 + b] = x[(b*Tz + t)*Ez + tid];
  }
  __syncthreads();
  int cs = tid & 31, rq = tid >> 5;            // 32 c-slots (4 cols), 8 b-quads... rq in 0..7
  float4 accv[4];
  #pragma unroll
  for (int jc = 0; jc < 4; ++jc) accv[jc] = make_float4(0.f,0.f,0.f,0.f);
  // rq covers b-quad: but we have 8 rq and only 8 quads of 4 b = 32 b. OK.
  for (int e = 0; e < 256; ++e){
    float4 xv = *(const float4*)&xT[e*36 + 4*(rq & 7)];
    float4 wv = *(const float4*)&Wx[e*2048 + c0 + 4*cs];
    accv[0].x = fmaf(xv.x, wv.x, accv[0].x); accv[0].y = fmaf(xv.y, wv.x, accv[0].y);
    accv[0].z = fmaf(xv.z, wv.x, accv[0].z); accv[0].w = fmaf(xv.w, wv.x, accv[0].w);
    accv[1].x = fmaf(xv.x, wv.y, accv[1].x); accv[1].y = fmaf(xv.y, wv.y, accv[1].y);
    accv[1].z = fmaf(xv.z, wv.y, accv[1].z); accv[1].w = fmaf(xv.w, wv.y, accv[1].w);
    accv[2].x = fmaf(xv.x, wv.z, accv[2].x); accv[2].y = fmaf(xv.y, wv.z, accv[2].y);
    accv[2].z = fmaf(xv.z, wv.z, accv[2].z); accv[2].w = fmaf(xv.w, wv.z, accv[2].w);
    accv[3].x = fmaf(xv.x, wv.w, accv[3].x); accv[3].y = fmaf(xv.y, wv.w, accv[3].y);
    accv[3].z = fmaf(xv.z, wv.w, accv[3].z); accv[3].w = fmaf(xv.w, wv.w, accv[3].w);
  }
  #pragma unroll
  for (int jc = 0; jc < 4; ++jc){
    int col = c0 + 4*cs + jc;
    float bv = cb[col];
    float4 o = accv[jc];
    o.x += bv; o.y += bv; o.z += bv; o.w += bv;
    *(float4*)&xzT[(t*2048 + col)*32 + 4*rq] = o;   // 4 consecutive b
  }
}

// ---------------- one recurrence step ----------------
// 256 blocks, block owns hidden cols j0=2*bid, j0+1 (z-cols j0+512g).
// hbuf layout: h[k*32 + b] (k-major). cbuf same.
__global__ __launch_bounds__(256) void k_step(int t,
    const float* __restrict__ xzT, const float* __restrict__ WhT,
    const float* __restrict__ d0a, const float* __restrict__ d1a,
    const float* __restrict__ hprev, float* __restrict__ hnext,
    float* __restrict__ cbuf, float* __restrict__ out)
{
  __shared__ float part[32*264];
  __shared__ float zL[32*8];
  int tid = threadIdx.x;
  int cl = tid & 7, ks = tid >> 3;             // 8 z-cols x 32 k-slices
  int j0 = blockIdx.x * 2;
  int col = ((cl >> 1) << 9) + j0 + (cl & 1);  // gate*512 + j
  float wreg[16];
  #pragma unroll
  for (int m = 0; m < 16; ++m) wreg[m] = WhT[col*512 + 32*m + ks];
  float acc[32];
  #pragma unroll
  for (int b = 0; b < 32; ++b) acc[b] = 0.0f;
  #pragma unroll
  for (int m = 0; m < 16; ++m){
    const float4* hp = (const float4*)(hprev + (32*m + ks)*32);
    float w = wreg[m];
    #pragma unroll
    for (int bq = 0; bq < 8; ++bq){
      float4 hv = hp[bq];
      acc[4*bq+0] = fmaf(hv.x, w, acc[4*bq+0]);
      acc[4*bq+1] = fmaf(hv.y, w, acc[4*bq+1]);
      acc[4*bq+2] = fmaf(hv.z, w, acc[4*bq+2]);
      acc[4*bq+3] = fmaf(hv.w, w, acc[4*bq+3]);
    }
  }
  #pragma unroll
  for (int b = 0; b < 32; ++b) part[b*264 + ks*8 + cl] = acc[b];
  __syncthreads();
  {
    int cl2 = tid & 7, b = tid >> 3;
    float s = 0.0f;
    #pragma unroll
    for (int k2 = 0; k2 < 32; ++k2) s += part[b*264 + k2*8 + cl2];
    int col2 = ((cl2 >> 1) << 9) + j0 + (cl2 & 1);
    s += xzT[(t*2048 + col2)*32 + b];
    zL[b*8 + cl2] = s;
  }
  __syncthreads();
  if (tid < 64){
    int b = tid & 31, jj = tid >> 5;
    int j = j0 + jj;
    float zi = zL[b*8 + 0 + jj];
    float zf = zL[b*8 + 2 + jj];
    float zg = zL[b*8 + 4 + jj];
    float zo = zL[b*8 + 6 + jj];
    float cold = cbuf[j*32 + b];
    float hold = hprev[j*32 + b];
    float ccand = sigf(zf)*cold + sigf(zi)*tanhfast(zg);
    float hcand = sigf(zo)*tanhfast(ccand);
    float dv0 = d0a[t*32 + b], dv1 = d1a[t*32 + b];
    hnext[j*32 + b] = dv0*hcand + dv1*hold;
    cbuf[j*32 + b]  = dv0*ccand + dv1*cold;
    out[b*(Tz*Hz) + t*Hz + j] = hcand;
  }
}

extern "C" void kernel_launch(void* const* d_in, const int* in_sizes, int n_in,
                              void* d_out, int out_size, void* d_ws, size_t ws_size,
                              hipStream_t stream)
{
  const float* x       = (const float*)d_in[0];
  const float* conv1_w = (const float*)d_in[1];
  const float* conv1_b = (const float*)d_in[2];
  const float* conv2_w = (const float*)d_in[3];
  const float* conv2_b = (const float*)d_in[4];
  const float* conv3_w = (const float*)d_in[5];
  const float* conv3_b = (const float*)d_in[6];
  const float* rev_Wx  = (const float*)d_in[7];
  const float* rev_Wh  = (const float*)d_in[8];
  const float* rev_b   = (const float*)d_in[9];
  const float* d0_W    = (const float*)d_in[10];
  const float* d0_b    = (const float*)d_in[11];
  const float* d1_W    = (const float*)d_in[12];
  const float* d1_b    = (const float*)d_in[13];
  const float* cell_Wx = (const float*)d_in[14];
  const float* cell_Wh = (const float*)d_in[15];
  const float* cell_b  = (const float*)d_in[16];
  const float* gumbel  = (const float*)d_in[17];
  float* out = (float*)d_out;

  char* ws = (char*)d_ws;
  size_t off = 0;
  float* xzT  = (float*)(ws + off); off += (size_t)Tz*2048*Bz*4;       // 134,217,728
  float* feat = (float*)(ws + off); off += (size_t)Tz*Bz*FCH*4;        // 29,229,056
  float* WhT  = (float*)(ws + off); off += (size_t)Hz*2048*4;          // 4,194,304
  float* rxw  = (float*)(ws + off); off += (size_t)Tz*Bz*40*4;         // 2,621,440
  float* hid  = (float*)(ws + off); off += (size_t)Tz*Bz*100*4;        // 6,553,600
  float* d0a  = (float*)(ws + off); off += (size_t)Tz*Bz*4;
  float* d1a  = (float*)(ws + off); off += (size_t)Tz*Bz*4;
  float* hb0  = (float*)(ws + off); off += (size_t)Hz*Bz*4;
  float* hb1  = (float*)(ws + off); off += (size_t)Hz*Bz*4;
  float* cbuf = (float*)(ws + off); off += (size_t)Hz*Bz*4;

  // zero-init: feat row T-1 (ff tail is zeros), h0, c0
  hipMemsetAsync(feat + (size_t)(Tz-1)*Bz*FCH, 0, Bz*FCH*4, stream);
  hipMemsetAsync(hb0, 0, Hz*Bz*4, stream);
  hipMemsetAsync(cbuf, 0, Hz*Bz*4, stream);

  k_transpose_wh<<<4096, 256, 0, stream>>>(cell_Wh, WhT);
  k_conv<<<512, 256, 0, stream>>>(x, conv1_w, conv1_b, conv2_w, conv2_b,
                                  conv3_w, conv3_b, rev_Wx, feat, rxw);
  k_featx<<<16384, 256, 0, stream>>>(x, feat);
  k_rev<<<32, 64, 0, stream>>>(rxw, rev_Wh, rev_b, feat);
  k_hid<<<512, 256, 0, stream>>>(feat, d0_W, d0_b, hid);
  k_pi<<<256, 128, 0, stream>>>(hid, d1_W, d1_b, gumbel, d0a, d1a);
  k_xz<<<8192, 256, 0, stream>>>(x, cell_Wx, cell_b, xzT);

  for (int t = 0; t < Tz; ++t){
    const float* hp = (t & 1) ? hb1 : hb0;
    float* hn       = (t & 1) ? hb0 : hb1;
    k_step<<<256, 256, 0, stream>>>(t, xzT, WhT, d0a, d1a, hp, hn, cbuf, out);
  }
}